// Round 10
// baseline (242.224 us; speedup 1.0000x reference)
//
#include <hip/hip_runtime.h>
#include <stdint.h>

#define B_ 64
#define T_ 2048
#define D_ 256
#define U_ 256
#define BT 128            // T rows per score_ctx block
#define NT (BT / 16)      // 8 tiles of 16 rows
#define TC (T_ / BT)      // 16 chunks per batch
#define SHIFT_ 8.0f       // fixed softmax shift; |score| <= sum|V_w| ~ 10 -> exp(s-8) fp32-safe

typedef _Float16 half8   __attribute__((ext_vector_type(8)));
typedef float    floatx4 __attribute__((ext_vector_type(4)));

typedef const __attribute__((address_space(1))) void cg_void;   // global src for DMA
typedef __attribute__((address_space(3))) void       ls_void;   // LDS dst for DMA

// ---------------- Kernel 1 (merged): qproj (blocks 0..63) + w2t (blocks 64..127) ----------
__global__ void prep_kernel(const float* __restrict__ query,
                            const float* __restrict__ W1_w,
                            const float* __restrict__ W1_b,
                            const float* __restrict__ W2_b,
                            const float* __restrict__ W2_w,
                            float* __restrict__ qb,
                            _Float16* __restrict__ w2t) {
    __shared__ float qrow[D_];
    __shared__ float tile[32][33];
    if (blockIdx.x < 64) {
        // qb[b,u] = query[b]·W1[:,u] + W1_b[u] + W2_b[u]
        const int b = blockIdx.x;
        const int u = threadIdx.x;           // 256 == U_
        qrow[u] = query[b * D_ + u];
        __syncthreads();
        float a0 = 0.f, a1 = 0.f, a2 = 0.f, a3 = 0.f;
#pragma unroll 4
        for (int d = 0; d < D_; d += 4) {
            a0 += qrow[d    ] * W1_w[(d    ) * U_ + u];
            a1 += qrow[d + 1] * W1_w[(d + 1) * U_ + u];
            a2 += qrow[d + 2] * W1_w[(d + 2) * U_ + u];
            a3 += qrow[d + 3] * W1_w[(d + 3) * U_ + u];
        }
        qb[b * U_ + u] = (a0 + a1) + (a2 + a3) + W1_b[u] + W2_b[u];
    } else {
        // w2t[u,d] = (fp16) W2[d,u]
        const int bid = blockIdx.x - 64;
        const int tu = bid & 7;              // u tile
        const int td = bid >> 3;             // d tile
        const int c  = threadIdx.x & 31;
        const int r0 = threadIdx.x >> 5;     // 0..7
#pragma unroll
        for (int i = 0; i < 4; ++i) {
            int r = r0 + i * 8;
            tile[r][c] = W2_w[(td * 32 + r) * U_ + tu * 32 + c];
        }
        __syncthreads();
#pragma unroll
        for (int i = 0; i < 4; ++i) {
            int r = r0 + i * 8;              // u within tile
            w2t[(tu * 32 + r) * D_ + td * 32 + c] = (_Float16)tile[c][r];
        }
    }
}

// ---------------- Kernel 2 (fused): scores + fixed-shift partial softmax context ----------------
// Byte-for-byte the R6 kernel (80us, passed, VGPR=128, FETCH=67MB) with ONE change:
// bfrag REGISTER PIN. R6 theory: VGPR_Count=128 < ~180 needed for resident bfrag[4][8]
// => compiler REMATERIALIZES W2 fragments from L2 inside every tile (~32 hidden
// global_load_dwordx4/wave/tile, ~200cyc each, FETCH-invisible since w2t is L2-hot).
// Fix: pass each fragment through an empty asm volatile("" : "+v") after the load —
// zero instructions emitted, but the value becomes asm-defined so it CANNOT be remat'd;
// allocator must keep all 128 bfrag VGPRs live (256-VGPR tier, 2 waves/SIMD — which is
// all we ever measured anyway). R8 lesson: no hand-written load asm (core dump).
// (R9 bench was an infra failure — container died twice; this is the same kernel resubmitted.)
__launch_bounds__(256, 2)
__global__ void score_ctx_kernel(const float* __restrict__ values,
                                 const _Float16* __restrict__ w2t,
                                 const float* __restrict__ qb,
                                 const float* __restrict__ V_w,
                                 float* __restrict__ scores,
                                 float* __restrict__ pctx,
                                 float* __restrict__ pl) {
    __shared__ __align__(16) float buf[2][16 * D_];    // 2 x 16KB fp32 tiles
    __shared__ __align__(16) float s_part2[16][4];     // [row t][wave] partial scores
    __shared__ float sbuf[BT];                          // raw scores for this chunk

    const int b     = blockIdx.y;
    const int chunk = blockIdx.x;
    const int tid   = threadIdx.x;
    const int wave  = tid >> 6;
    const int lane  = tid & 63;
    const int n16   = lane & 15;
    const int quad  = lane >> 4;
    const int u0    = wave * 64;

    // --- W2 B-fragments, register-stationary (verified layout) + remat-blocking pin ---
    half8 bfrag[4][8];
#pragma unroll
    for (int ut = 0; ut < 4; ++ut) {
        const int u = u0 + ut * 16 + n16;
#pragma unroll
        for (int k = 0; k < 8; ++k)
            bfrag[ut][k] = *(const half8*)(w2t + u * D_ + k * 32 + quad * 8);
    }
#pragma unroll
    for (int ut = 0; ut < 4; ++ut)
#pragma unroll
        for (int k = 0; k < 8; ++k)
            asm volatile("" : "+v"(bfrag[ut][k]));   // zero-cost: forbid rematerialization

    float qbv[4], vwv[4];
#pragma unroll
    for (int ut = 0; ut < 4; ++ut) {
        const int u = u0 + ut * 16 + n16;
        qbv[ut] = qb[b * U_ + u];
        vwv[ut] = V_w[u];
    }

    const float* vbase = values + (size_t)b * T_ * D_ + (size_t)chunk * BT * D_;

    // MFMA A-operand: global chunk c0=k*8+quad*2 lives at LDS chunk k*8 + ((quad*2)^swz)
    // since swz<8. Hoisted per-lane bases; k-loop strides 8 chunks = 32 floats (k<<5).
    const int e0 = (quad * 2) ^ (n16 & 7);
    const int e1 = e0 ^ 1;

    // Context mapping for d = tid: global chunk g=tid>>2 at LDS chunk g^(row&7).
    const int g = tid >> 2, lo = tid & 3;
    int co[8];
#pragma unroll
    for (int s = 0; s < 8; ++s) co[s] = (((g ^ s) & 63) << 2) + lo;

    float c = 0.f;    // context accumulator: this thread owns d = tid
    float l = 0.f;    // sum of exp(s - SHIFT_) (identical in all threads)

    // stage one 16-row tile: 16 wave-level DMA ops, 4 per wave (wave-uniform LDS base)
    auto stage = [&](int tile, int bi) {
        const float* src = vbase + tile * 16 * D_;
#pragma unroll
        for (int i = 0; i < 4; ++i) {
            const int r = i * 4 + wave;                          // wave-uniform row
            const float* gp = src + r * D_ + ((lane ^ (r & 7)) << 2);
            float* lp = &buf[bi][r * D_];
            __builtin_amdgcn_global_load_lds((cg_void*)gp, (ls_void*)lp, 16, 0, 0);
        }
    };

    stage(0, 0);

#pragma unroll 1
    for (int tile = 0; tile < NT; ++tile) {
        const int cur = tile & 1;
        // B1: tile 'cur' staged (drain own DMA) + all waves past phase-2 of tile-1.
        asm volatile("s_waitcnt vmcnt(0) lgkmcnt(0)" ::: "memory");
        __builtin_amdgcn_s_barrier();
        asm volatile("" ::: "memory");

        // prefetch tile+1 into the other slot (its last readers passed B1 above);
        // these 4 loads stay in flight through this whole tile's compute.
        if (tile + 1 < NT) stage(tile + 1, cur ^ 1);

        // --- phase 1: MFMA Vp[16 x 64chunk], A from swizzled fp32 LDS, cvt in regs ---
        const float* a0p = &buf[cur][n16 * D_] + (e0 << 2);
        const float* a1p = &buf[cur][n16 * D_] + (e1 << 2);
        floatx4 acc[4] = {};
#pragma unroll
        for (int k = 0; k < 8; ++k) {
            floatx4 q0 = *(const floatx4*)(a0p + (k << 5));   // k*8 chunks = 128B imm offset
            floatx4 q1 = *(const floatx4*)(a1p + (k << 5));
            half8 a;
            a[0] = (_Float16)q0.x; a[1] = (_Float16)q0.y;
            a[2] = (_Float16)q0.z; a[3] = (_Float16)q0.w;
            a[4] = (_Float16)q1.x; a[5] = (_Float16)q1.y;
            a[6] = (_Float16)q1.z; a[7] = (_Float16)q1.w;
#pragma unroll
            for (int ut = 0; ut < 4; ++ut)
                acc[ut] = __builtin_amdgcn_mfma_f32_16x16x32_f16(a, bfrag[ut][k], acc[ut], 0, 0, 0);
        }

        // --- epilogue: tanh + dot with V_w, reduce over u (n16) ---
        float part[4];
#pragma unroll
        for (int r = 0; r < 4; ++r) {
            float sa = 0.f;
#pragma unroll
            for (int ut = 0; ut < 4; ++ut) {
                float x  = acc[ut][r] + qbv[ut];
                float e  = __expf(2.f * x);
                float th = 1.f - __fdividef(2.f, e + 1.f);   // tanh(x)
                sa += th * vwv[ut];
            }
            part[r] = sa;
        }
#pragma unroll
        for (int m = 1; m < 16; m <<= 1)
#pragma unroll
            for (int r = 0; r < 4; ++r)
                part[r] += __shfl_xor(part[r], m, 16);
        if (n16 == 0) {
#pragma unroll
            for (int r = 0; r < 4; ++r)
                s_part2[quad * 4 + r][wave] = part[r];       // row t = quad*4+r
        }

        // B2: s_part2 visible (lgkm-only; prefetch DMA stays in flight)
        asm volatile("s_waitcnt lgkmcnt(0)" ::: "memory");
        __builtin_amdgcn_s_barrier();
        asm volatile("" ::: "memory");

        // --- phase 2: every thread computes the 16 weights + context FMA ---
        const float* bufp = &buf[cur][0];
        const float* sp2  = &s_part2[0][0];
#pragma unroll
        for (int t = 0; t < 16; ++t) {
            floatx4 sp = *(const floatx4*)(sp2 + t * 4);     // wave-uniform -> broadcast
            float sv = (sp.x + sp.y) + (sp.z + sp.w);
            float w  = __expf(sv - SHIFT_);
            l += w;
            c += w * bufp[t * D_ + co[t & 7]];               // imm offset t*1024B
        }
        if (tid < 16) {
            floatx4 sp = *(const floatx4*)(sp2 + tid * 4);
            sbuf[tile * 16 + tid] = (sp.x + sp.y) + (sp.z + sp.w);
        }
    }

    __syncthreads();   // sbuf visible
    pctx[(b * TC + chunk) * D_ + tid] = c;
    if (tid < BT) scores[b * T_ + chunk * BT + tid] = sbuf[tid];
    if (tid == 0) pl[b * TC + chunk] = l;
}

// ---------------- Kernel 3: combine partials -> ctx, attn ----------------
__global__ void finalize_kernel(const float* __restrict__ pctx,
                                const float* __restrict__ pl,
                                const float* __restrict__ scores,
                                float* __restrict__ ctx,
                                float* __restrict__ attn) {
    const int b = blockIdx.x, tid = threadIdx.x;   // 256 threads
    float L = 0.f;
#pragma unroll
    for (int i = 0; i < TC; ++i) L += pl[b * TC + i];
    float s = 0.f;
#pragma unroll
    for (int i = 0; i < TC; ++i) s += pctx[(b * TC + i) * D_ + tid];
    const float invL = __fdividef(1.f, L);
    ctx[b * D_ + tid] = s * invL;
#pragma unroll
    for (int j = 0; j < T_ / 256; ++j) {
        const int t = j * 256 + tid;
        attn[b * T_ + t] = __expf(scores[b * T_ + t] - SHIFT_) * invL;
    }
}

extern "C" void kernel_launch(void* const* d_in, const int* in_sizes, int n_in,
                              void* d_out, int out_size, void* d_ws, size_t ws_size,
                              hipStream_t stream) {
    const float* query  = (const float*)d_in[0];
    const float* values = (const float*)d_in[1];
    const float* W1_w   = (const float*)d_in[2];
    const float* W1_b   = (const float*)d_in[3];
    const float* W2_w   = (const float*)d_in[4];
    const float* W2_b   = (const float*)d_in[5];
    const float* V_w    = (const float*)d_in[6];
    // d_in[7] = V_b: softmax is shift-invariant -> no effect on either output.

    float* out  = (float*)d_out;
    float* ctx  = out;                  // [B, D]
    float* attn = out + B_ * D_;        // [B, T]

    char* ws = (char*)d_ws;
    float*    qb     = (float*)ws;                               // B*U fp32       (64 KB)
    _Float16* w2t    = (_Float16*)(ws + (64 << 10));             // U*D fp16       (128 KB)
    float*    scores = (float*)(ws + (192 << 10));               // B*T fp32       (512 KB)
    float*    pctx   = (float*)(ws + (704 << 10));               // B*TC*D fp32    (1 MB)
    float*    pl     = (float*)(ws + (1728 << 10));              // B*TC fp32      (4 KB)

    prep_kernel     <<<dim3(128),     dim3(256), 0, stream>>>(query, W1_w, W1_b, W2_b, W2_w, qb, w2t);
    score_ctx_kernel<<<dim3(TC, B_),  dim3(256), 0, stream>>>(values, w2t, qb, V_w, scores, pctx, pl);
    finalize_kernel <<<dim3(B_),      dim3(256), 0, stream>>>(pctx, pl, scores, ctx, attn);
}